// Round 4
// baseline (917.545 us; speedup 1.0000x reference)
//
#include <hip/hip_runtime.h>
#include <cmath>

namespace {

typedef __bf16 bf16x8 __attribute__((ext_vector_type(8)));
typedef float f32x4 __attribute__((ext_vector_type(4)));

enum : int { N = 128, T = 32, D = 512, H = 1024, V = 16384, R = N * T, NP = V / 64 };

// ---- workspace layout (float units) ----
enum : size_t {
  OFF_XB    = 0,                                // 4096x512 bf16   -> 1,048,576 fl
  OFF_FEATB = OFF_XB + 1048576,                 // 128x512 bf16    -> 32,768
  OFF_H0B   = OFF_FEATB + 32768,                // 128x1024 bf16   -> 65,536
  OFF_HALLB = OFF_H0B + 65536,                  // 4096x1024 bf16  -> 2,097,152
  OFF_WPT   = OFF_HALLB + 2097152,              // 1024x512 bf16   -> 262,144
  OFF_WXT   = OFF_WPT + 262144,                 // 1024x512 bf16   -> 262,144
  OFF_WHT   = OFF_WXT + 262144,                 // 1024x1024 bf16  -> 524,288
  OFF_WVT   = OFF_WHT + 524288,                 // 16384x1024 bf16 -> 8,388,608
  OFF_XW    = OFF_WVT + 8388608,                // 4096x1024 f32   -> 4,194,304
  OFF_PMAX  = OFF_XW + 4194304,                 // 4096x256 f32
  OFF_PSUM  = OFF_PMAX + 1048576,
  OFF_BLK   = OFF_PSUM + 1048576,               // 1024
  OFF_BAR   = OFF_BLK + 1024,                   // 8 ints (barrier cells)
};

__device__ inline unsigned short f2b(float x) {
  union { float f; unsigned u; } v; v.f = x;
  unsigned r = v.u + 0x7fffu + ((v.u >> 16) & 1u);
  return (unsigned short)(r >> 16);
}
__device__ inline float b2f(unsigned short b) {
  union { unsigned u; float f; } v; v.u = ((unsigned)b) << 16; return v.f;
}

#define GLOAD_LDS16(gptr, lptr)                                            \
  __builtin_amdgcn_global_load_lds(                                        \
      (const __attribute__((address_space(1))) unsigned int*)(gptr),       \
      (__attribute__((address_space(3))) unsigned int*)(lptr), 16, 0, 0)

// ---------- convert + transpose: dst[n][k] = bf16(src[k][n]) ----------
__global__ __launch_bounds__(256) void k_cvt_t(const float* __restrict__ src,
                                               unsigned short* __restrict__ dst,
                                               int Ks, int Ns) {
  __shared__ float tile[32][33];
  int tx = threadIdx.x & 31, ty = threadIdx.x >> 5;
  int n0 = blockIdx.x * 32, k0 = blockIdx.y * 32;
#pragma unroll
  for (int i = 0; i < 4; ++i)
    tile[ty + i * 8][tx] = src[(size_t)(k0 + ty + i * 8) * Ns + n0 + tx];
  __syncthreads();
  int kc = threadIdx.x & 15;    // ushort2 index in k
  int nr0 = threadIdx.x >> 4;   // 0..15
#pragma unroll
  for (int i = 0; i < 2; ++i) {
    int nr = nr0 + i * 16;
    ushort2 o;
    o.x = f2b(tile[kc * 2][nr]);
    o.y = f2b(tile[kc * 2 + 1][nr]);
    *reinterpret_cast<ushort2*>(dst + (size_t)(n0 + nr) * Ks + k0 + kc * 2) = o;
  }
}

// ---------- elementwise fp32 -> bf16 (2 elems/thread) ----------
__global__ __launch_bounds__(256) void k_cvt(const float* __restrict__ src,
                                             unsigned short* __restrict__ dst) {
  int i = (blockIdx.x * 256 + threadIdx.x) * 2;
  float2 v = *reinterpret_cast<const float2*>(src + i);
  ushort2 o; o.x = f2b(v.x); o.y = f2b(v.y);
  *reinterpret_cast<ushort2*>(dst + i) = o;
}

// ---------- gather embeddings + cvt ----------
__global__ __launch_bounds__(256) void k_gather(const int* __restrict__ cap,
                                                const float* __restrict__ Wemb,
                                                unsigned short* __restrict__ XB) {
  int idx = blockIdx.x * 256 + threadIdx.x;
  int r = idx >> 8;
  int w2 = (idx & 255) * 2;
  int n = r >> 5, t = r & 31;
  const float* srow = Wemb + (size_t)cap[n * 33 + t] * D;
  float2 v = *reinterpret_cast<const float2*>(srow + w2);
  ushort2 o; o.x = f2b(v.x); o.y = f2b(v.y);
  *reinterpret_cast<ushort2*>(XB + (size_t)r * D + w2) = o;
}

// ---------- bf16 MFMA GEMM: C = A * B^T (B is [N][K]), XOR-swizzled LDS ----------
// EPI: 0 = f32 store + bias; 1 = bf16 store + bias; 3 = fused row (max,sumexp)
template <int BM, int BN, int WM, int WN, int EPI>
__global__ __launch_bounds__(256) void gemm_bt(
    const unsigned short* __restrict__ A, int lda,
    const unsigned short* __restrict__ B, int K,
    void* __restrict__ C, int ldc,
    const float* __restrict__ bias,
    float* __restrict__ pmax, float* __restrict__ psum) {
  constexpr int BK = 64;
  constexpr int WAVES_N = BN / WN;
  constexpr int NW = (BM / WM) * (BN / WN);
  constexpr int FM = WM / 16, FN = WN / 16;
  __shared__ __align__(16) unsigned short As[BM * BK];
  __shared__ __align__(16) unsigned short Bs[BN * BK];
  int tid = threadIdx.x, lane = tid & 63, wave = tid >> 6;
  int wr = wave / WAVES_N, wc = wave % WAVES_N;
  int row0 = blockIdx.y * BM, col0 = blockIdx.x * BN;

  f32x4 acc[FM][FN] = {};
  const unsigned short* Ab = A + (size_t)row0 * lda;
  const unsigned short* Bb = B + (size_t)col0 * K;
  int srow = lane >> 3;
  int skof = (((lane & 7) ^ (lane >> 3))) * 8;   // inverse-swizzled source granule

  for (int k0 = 0; k0 < K; k0 += BK) {
    __syncthreads();
#pragma unroll
    for (int c = wave; c < BM / 8; c += NW)
      GLOAD_LDS16(Ab + (size_t)(c * 8 + srow) * lda + k0 + skof, As + c * 512);
#pragma unroll
    for (int c = wave; c < BN / 8; c += NW)
      GLOAD_LDS16(Bb + (size_t)(c * 8 + srow) * K + k0 + skof, Bs + c * 512);
    asm volatile("s_waitcnt vmcnt(0)" ::: "memory");
    __syncthreads();
#pragma unroll
    for (int kk = 0; kk < 2; ++kk) {
      int g = ((kk * 4 + (lane >> 4)) ^ (lane & 7)) * 8;  // swizzled read granule
      bf16x8 af[FM], bfr[FN];
#pragma unroll
      for (int m = 0; m < FM; ++m)
        af[m] = *reinterpret_cast<const bf16x8*>(
            &As[(wr * WM + m * 16 + (lane & 15)) * BK + g]);
#pragma unroll
      for (int n = 0; n < FN; ++n)
        bfr[n] = *reinterpret_cast<const bf16x8*>(
            &Bs[(wc * WN + n * 16 + (lane & 15)) * BK + g]);
#pragma unroll
      for (int m = 0; m < FM; ++m)
#pragma unroll
        for (int n = 0; n < FN; ++n)
          acc[m][n] = __builtin_amdgcn_mfma_f32_16x16x32_bf16(af[m], bfr[n], acc[m][n], 0, 0, 0);
    }
  }

  int lr4 = (lane >> 4) * 4, lc = lane & 15;
  if constexpr (EPI == 3) {
    float bb[FN];
#pragma unroll
    for (int n = 0; n < FN; ++n) bb[n] = bias[col0 + wc * WN + n * 16 + lc];
    int p = (col0 + wc * WN) >> 6;  // WN == 64
#pragma unroll
    for (int m = 0; m < FM; ++m) {
#pragma unroll
      for (int j = 0; j < 4; ++j) {
        int r = row0 + wr * WM + m * 16 + lr4 + j;
        float vs[FN], vmax = -1e30f;
#pragma unroll
        for (int n = 0; n < FN; ++n) {
          vs[n] = acc[m][n][j] + bb[n];
          vmax = fmaxf(vmax, vs[n]);
        }
#pragma unroll
        for (int off = 8; off >= 1; off >>= 1) vmax = fmaxf(vmax, __shfl_xor(vmax, off));
        float se = 0.f;
#pragma unroll
        for (int n = 0; n < FN; ++n) se += expf(vs[n] - vmax);
#pragma unroll
        for (int off = 8; off >= 1; off >>= 1) se += __shfl_xor(se, off);
        if (lc == 0) {
          pmax[(size_t)r * NP + p] = vmax;
          psum[(size_t)r * NP + p] = se;
        }
      }
    }
  } else {
#pragma unroll
    for (int m = 0; m < FM; ++m)
#pragma unroll
      for (int n = 0; n < FN; ++n) {
        int cg = col0 + wc * WN + n * 16 + lc;
        float bcol = bias[cg];
#pragma unroll
        for (int j = 0; j < 4; ++j) {
          int r = row0 + wr * WM + m * 16 + lr4 + j;
          float v = acc[m][n][j] + bcol;
          if constexpr (EPI == 0) ((float*)C)[(size_t)r * ldc + cg] = v;
          else ((unsigned short*)C)[(size_t)r * ldc + cg] = f2b(v);
        }
      }
  }
}

// ---------- persistent RNN: all 32 steps, one dispatch ----------
// 128 blocks = 4 n-groups(32 rows) x 32 h-groups(32 cols). Wh slice LDS-resident.
// Grid barrier between steps: 8-cell device-scope atomic counter + threadfence.
__global__ __launch_bounds__(256, 1) void k_rnn_persist(
    const unsigned short* __restrict__ h0B,
    const unsigned short* __restrict__ WhT,   // [outcol][k] bf16
    const float* __restrict__ xW,             // [R][H] f32
    unsigned short* __restrict__ HALLB,       // [R][H] bf16
    int* __restrict__ cells) {
  __shared__ __align__(16) unsigned short WhS[32 * 1024];
  __shared__ __align__(16) unsigned short AS[32 * 1024];
  const int tid = threadIdx.x, lane = tid & 63, wave = tid >> 6;
  const int bn = blockIdx.x >> 5, bh = blockIdx.x & 31;
  const int n0 = bn * 32, c0 = bh * 32;
  const int wr = wave >> 1, wc = wave & 1;
  const int hi = lane >> 4, lo = lane & 15;

  // stage Wh slice once, swizzled: LDS granule g of row r <- src granule g^(r&7)
  for (int c = wave; c < 64; c += 4) {
    int row = c >> 1, half = c & 1;
    int sg = (half * 64 + lane) ^ (row & 7);
    GLOAD_LDS16(WhT + (size_t)(c0 + row) * 1024 + sg * 8,
                WhS + row * 1024 + half * 512);
  }

  const int acol = c0 + wc * 16 + lo;
  const unsigned short* ar = AS + (size_t)(wr * 16 + lo) * 1024;
  const unsigned short* br = WhS + (size_t)(wc * 16 + lo) * 1024;

  for (int t = 0; t < T; ++t) {
    const unsigned short* Abase = (t == 0) ? h0B : (HALLB + (size_t)(t - 1) * H);
    size_t astr = (t == 0) ? (size_t)H : (size_t)T * H;
    for (int c = wave; c < 64; c += 4) {
      int row = c >> 1, half = c & 1;
      int sg = (half * 64 + lane) ^ (row & 7);
      GLOAD_LDS16(Abase + (size_t)(n0 + row) * astr + sg * 8,
                  AS + row * 1024 + half * 512);
    }
    float xw[4];
#pragma unroll
    for (int j = 0; j < 4; ++j)
      xw[j] = xW[(size_t)((n0 + wr * 16 + hi * 4 + j) * T + t) * H + acol];
    asm volatile("s_waitcnt vmcnt(0)" ::: "memory");
    __syncthreads();

    f32x4 acc = {0.f, 0.f, 0.f, 0.f};
#pragma unroll
    for (int kk = 0; kk < 32; ++kk) {
      int g = ((kk * 4 + hi) ^ (lane & 7)) * 8;
      bf16x8 af = *reinterpret_cast<const bf16x8*>(ar + g);
      bf16x8 bf_ = *reinterpret_cast<const bf16x8*>(br + g);
      acc = __builtin_amdgcn_mfma_f32_16x16x32_bf16(af, bf_, acc, 0, 0, 0);
    }
#pragma unroll
    for (int j = 0; j < 4; ++j) {
      float v = tanhf(acc[j] + xw[j]);
      HALLB[(size_t)((n0 + wr * 16 + hi * 4 + j) * T + t) * H + acol] = f2b(v);
    }
    if (t + 1 < T) {
      __threadfence();          // release h_t (L2 writeback, cross-XCD)
      __syncthreads();          // all threads in block fenced
      if (tid == 0)
        __hip_atomic_fetch_add(&cells[blockIdx.x & 7], 1, __ATOMIC_RELAXED,
                               __HIP_MEMORY_SCOPE_AGENT);
      if (tid < 8) {
        int target = 16 * (t + 1);
        while (__hip_atomic_load(&cells[tid], __ATOMIC_RELAXED,
                                 __HIP_MEMORY_SCOPE_AGENT) < target)
          __builtin_amdgcn_s_sleep(1);
      }
      __syncthreads();
      __threadfence();          // acquire (invalidate local caches)
    }
  }
}

// ---------- combine partials + target dot -> per-block nll sums ----------
__global__ __launch_bounds__(256) void k_loss(const float* __restrict__ pmax,
                                              const float* __restrict__ psum,
                                              const unsigned short* __restrict__ HALLB,
                                              const unsigned short* __restrict__ WvT,
                                              const float* __restrict__ bv,
                                              const int* __restrict__ cap,
                                              float* __restrict__ blk) {
  int wave = threadIdx.x >> 6, lane = threadIdx.x & 63;
  int r = blockIdx.x * 4 + wave;
  float M = -1e30f;
  for (int i = lane; i < NP; i += 64) M = fmaxf(M, pmax[(size_t)r * NP + i]);
#pragma unroll
  for (int off = 32; off >= 1; off >>= 1) M = fmaxf(M, __shfl_xor(M, off));
  float S = 0.f;
  for (int i = lane; i < NP; i += 64) S += psum[(size_t)r * NP + i] * expf(pmax[(size_t)r * NP + i] - M);
#pragma unroll
  for (int off = 32; off >= 1; off >>= 1) S += __shfl_xor(S, off);
  float lse = M + logf(S);
  int n = r >> 5, t = r & 31;
  int tok = cap[n * 33 + t + 1];
  const unsigned short* hr = HALLB + (size_t)r * H + lane * 16;
  const unsigned short* wr_ = WvT + (size_t)tok * H + lane * 16;
  float d = 0.f;
#pragma unroll
  for (int i = 0; i < 16; ++i) d += b2f(hr[i]) * b2f(wr_[i]);
#pragma unroll
  for (int off = 32; off >= 1; off >>= 1) d += __shfl_xor(d, off);
  float nll = (tok != 0) ? (lse - (d + bv[tok])) : 0.f;
  __shared__ float red[4];
  if (lane == 0) red[wave] = nll;
  __syncthreads();
  if (threadIdx.x == 0) blk[blockIdx.x] = red[0] + red[1] + red[2] + red[3];
}

__global__ __launch_bounds__(256) void k_final(const float* __restrict__ blk,
                                               float* __restrict__ out) {
  __shared__ float red[256];
  float s = 0.f;
  for (int i = threadIdx.x; i < R / 4; i += 256) s += blk[i];
  red[threadIdx.x] = s;
  __syncthreads();
  for (int st = 128; st >= 1; st >>= 1) {
    if (threadIdx.x < st) red[threadIdx.x] += red[threadIdx.x + st];
    __syncthreads();
  }
  if (threadIdx.x == 0) out[0] = red[0] * (1.0f / 128.0f);
}

}  // namespace

extern "C" void kernel_launch(void* const* d_in, const int* in_sizes, int n_in,
                              void* d_out, int out_size, void* d_ws, size_t ws_size,
                              hipStream_t stream) {
  const float* feat = (const float*)d_in[0];
  const int*   cap  = (const int*)d_in[1];
  const float* Wp   = (const float*)d_in[2];
  const float* bp   = (const float*)d_in[3];
  const float* Wemb = (const float*)d_in[4];
  const float* Wx   = (const float*)d_in[5];
  const float* Wh   = (const float*)d_in[6];
  const float* b    = (const float*)d_in[7];
  const float* Wv   = (const float*)d_in[8];
  const float* bv   = (const float*)d_in[9];

  float* ws = (float*)d_ws;
  unsigned short* XB    = (unsigned short*)(ws + OFF_XB);
  unsigned short* featB = (unsigned short*)(ws + OFF_FEATB);
  unsigned short* h0B   = (unsigned short*)(ws + OFF_H0B);
  unsigned short* HALLB = (unsigned short*)(ws + OFF_HALLB);
  unsigned short* WpT   = (unsigned short*)(ws + OFF_WPT);
  unsigned short* WxT   = (unsigned short*)(ws + OFF_WXT);
  unsigned short* WhT   = (unsigned short*)(ws + OFF_WHT);
  unsigned short* WvT   = (unsigned short*)(ws + OFF_WVT);
  float* xW   = ws + OFF_XW;
  float* pmax = ws + OFF_PMAX;
  float* psum = ws + OFF_PSUM;
  float* blk  = ws + OFF_BLK;
  int*   bar  = (int*)(ws + OFF_BAR);

  hipMemsetAsync(bar, 0, 8 * sizeof(int), stream);

  // weight converts/transposes (bf16, B^T layout)
  hipLaunchKernelGGL(k_cvt_t, dim3(H / 32, D / 32), dim3(256), 0, stream, Wp, WpT, D, H);
  hipLaunchKernelGGL(k_cvt_t, dim3(H / 32, D / 32), dim3(256), 0, stream, Wx, WxT, D, H);
  hipLaunchKernelGGL(k_cvt_t, dim3(H / 32, H / 32), dim3(256), 0, stream, Wh, WhT, H, H);
  hipLaunchKernelGGL(k_cvt_t, dim3(V / 32, H / 32), dim3(256), 0, stream, Wv, WvT, H, V);
  hipLaunchKernelGGL(k_cvt, dim3(N * D / 512), dim3(256), 0, stream, feat, featB);
  hipLaunchKernelGGL(k_gather, dim3(R * D / 512), dim3(256), 0, stream, cap, Wemb, XB);

  // h0 = featB @ Wp^T + bp   (bf16 out)
  hipLaunchKernelGGL((gemm_bt<128, 128, 64, 64, 1>), dim3(H / 128, 1), dim3(256), 0, stream,
                     featB, D, WpT, D, (void*)h0B, H, bp, nullptr, nullptr);
  // xW = XB @ Wx^T + b   (f32 out)
  hipLaunchKernelGGL((gemm_bt<128, 128, 64, 64, 0>), dim3(H / 128, R / 128), dim3(256), 0, stream,
                     XB, D, WxT, D, (void*)xW, H, b, nullptr, nullptr);
  // full recurrence in one persistent dispatch
  hipLaunchKernelGGL(k_rnn_persist, dim3(128), dim3(256), 0, stream,
                     h0B, WhT, xW, HALLB, bar);
  // scores partials
  hipLaunchKernelGGL((gemm_bt<128, 128, 64, 64, 3>), dim3(V / 128, R / 128), dim3(256), 0, stream,
                     HALLB, H, WvT, H, nullptr, 0, bv, pmax, psum);
  hipLaunchKernelGGL(k_loss, dim3(R / 4), dim3(256), 0, stream,
                     pmax, psum, HALLB, WvT, bv, cap, blk);
  hipLaunchKernelGGL(k_final, dim3(1), dim3(256), 0, stream, blk, (float*)d_out);
}

// Round 5
// 420.326 us; speedup vs baseline: 2.1829x; 2.1829x over previous
//
#include <hip/hip_runtime.h>
#include <cmath>

namespace {

typedef __bf16 bf16x8 __attribute__((ext_vector_type(8)));
typedef float f32x4 __attribute__((ext_vector_type(4)));

enum : int { N = 128, T = 32, D = 512, H = 1024, V = 16384, R = N * T, NP = V / 64 };

// ---- workspace layout (float units) ----
enum : size_t {
  OFF_XB    = 0,                                // 4096x512 bf16   -> 1,048,576 fl
  OFF_FEATB = OFF_XB + 1048576,                 // 128x512 bf16    -> 32,768
  OFF_H0B   = OFF_FEATB + 32768,                // 128x1024 bf16   -> 65,536
  OFF_HALLB = OFF_H0B + 65536,                  // 4096x1024 bf16  -> 2,097,152
  OFF_WPT   = OFF_HALLB + 2097152,              // 1024x512 bf16   -> 262,144
  OFF_WXT   = OFF_WPT + 262144,                 // 1024x512 bf16   -> 262,144
  OFF_WHT   = OFF_WXT + 262144,                 // 1024x1024 bf16  -> 524,288
  OFF_WVT   = OFF_WHT + 524288,                 // 16384x1024 bf16 -> 8,388,608
  OFF_XW    = OFF_WVT + 8388608,                // 4096x1024 f32   -> 4,194,304
  OFF_PMAX  = OFF_XW + 4194304,                 // 4096x256 f32
  OFF_PSUM  = OFF_PMAX + 1048576,
  OFF_BLK   = OFF_PSUM + 1048576,               // 1024
  OFF_BAR   = OFF_BLK + 1024,                   // 512 ints (4 cells, 512B apart)
};

__device__ inline unsigned short f2b(float x) {
  union { float f; unsigned u; } v; v.f = x;
  unsigned r = v.u + 0x7fffu + ((v.u >> 16) & 1u);
  return (unsigned short)(r >> 16);
}
__device__ inline float b2f(unsigned short b) {
  union { unsigned u; float f; } v; v.u = ((unsigned)b) << 16; return v.f;
}

#define GLOAD_LDS16(gptr, lptr)                                            \
  __builtin_amdgcn_global_load_lds(                                        \
      (const __attribute__((address_space(1))) unsigned int*)(gptr),       \
      (__attribute__((address_space(3))) unsigned int*)(lptr), 16, 0, 0)

// ---------- convert + transpose: dst[n][k] = bf16(src[k][n]) ----------
__global__ __launch_bounds__(256) void k_cvt_t(const float* __restrict__ src,
                                               unsigned short* __restrict__ dst,
                                               int Ks, int Ns) {
  __shared__ float tile[32][33];
  int tx = threadIdx.x & 31, ty = threadIdx.x >> 5;
  int n0 = blockIdx.x * 32, k0 = blockIdx.y * 32;
#pragma unroll
  for (int i = 0; i < 4; ++i)
    tile[ty + i * 8][tx] = src[(size_t)(k0 + ty + i * 8) * Ns + n0 + tx];
  __syncthreads();
  int kc = threadIdx.x & 15;    // ushort2 index in k
  int nr0 = threadIdx.x >> 4;   // 0..15
#pragma unroll
  for (int i = 0; i < 2; ++i) {
    int nr = nr0 + i * 16;
    ushort2 o;
    o.x = f2b(tile[kc * 2][nr]);
    o.y = f2b(tile[kc * 2 + 1][nr]);
    *reinterpret_cast<ushort2*>(dst + (size_t)(n0 + nr) * Ks + k0 + kc * 2) = o;
  }
}

// ---------- elementwise fp32 -> bf16 (2 elems/thread) ----------
__global__ __launch_bounds__(256) void k_cvt(const float* __restrict__ src,
                                             unsigned short* __restrict__ dst) {
  int i = (blockIdx.x * 256 + threadIdx.x) * 2;
  float2 v = *reinterpret_cast<const float2*>(src + i);
  ushort2 o; o.x = f2b(v.x); o.y = f2b(v.y);
  *reinterpret_cast<ushort2*>(dst + i) = o;
}

// ---------- gather embeddings + cvt ----------
__global__ __launch_bounds__(256) void k_gather(const int* __restrict__ cap,
                                                const float* __restrict__ Wemb,
                                                unsigned short* __restrict__ XB) {
  int idx = blockIdx.x * 256 + threadIdx.x;
  int r = idx >> 8;
  int w2 = (idx & 255) * 2;
  int n = r >> 5, t = r & 31;
  const float* srow = Wemb + (size_t)cap[n * 33 + t] * D;
  float2 v = *reinterpret_cast<const float2*>(srow + w2);
  ushort2 o; o.x = f2b(v.x); o.y = f2b(v.y);
  *reinterpret_cast<ushort2*>(XB + (size_t)r * D + w2) = o;
}

// ---------- bf16 MFMA GEMM: C = A * B^T (B is [N][K]), XOR-swizzled LDS ----------
// EPI: 0 = f32 store + bias; 1 = bf16 store + bias; 3 = fused row (max,sumexp)
template <int BM, int BN, int WM, int WN, int EPI>
__global__ __launch_bounds__(256) void gemm_bt(
    const unsigned short* __restrict__ A, int lda,
    const unsigned short* __restrict__ B, int K,
    void* __restrict__ C, int ldc,
    const float* __restrict__ bias,
    float* __restrict__ pmax, float* __restrict__ psum) {
  constexpr int BK = 64;
  constexpr int WAVES_N = BN / WN;
  constexpr int NW = (BM / WM) * (BN / WN);
  constexpr int FM = WM / 16, FN = WN / 16;
  __shared__ __align__(16) unsigned short As[BM * BK];
  __shared__ __align__(16) unsigned short Bs[BN * BK];
  int tid = threadIdx.x, lane = tid & 63, wave = tid >> 6;
  int wr = wave / WAVES_N, wc = wave % WAVES_N;
  int row0 = blockIdx.y * BM, col0 = blockIdx.x * BN;

  f32x4 acc[FM][FN] = {};
  const unsigned short* Ab = A + (size_t)row0 * lda;
  const unsigned short* Bb = B + (size_t)col0 * K;
  int srow = lane >> 3;
  int skof = (((lane & 7) ^ (lane >> 3))) * 8;   // inverse-swizzled source granule

  for (int k0 = 0; k0 < K; k0 += BK) {
    __syncthreads();
#pragma unroll
    for (int c = wave; c < BM / 8; c += NW)
      GLOAD_LDS16(Ab + (size_t)(c * 8 + srow) * lda + k0 + skof, As + c * 512);
#pragma unroll
    for (int c = wave; c < BN / 8; c += NW)
      GLOAD_LDS16(Bb + (size_t)(c * 8 + srow) * K + k0 + skof, Bs + c * 512);
    asm volatile("s_waitcnt vmcnt(0)" ::: "memory");
    __syncthreads();
#pragma unroll
    for (int kk = 0; kk < 2; ++kk) {
      int g = ((kk * 4 + (lane >> 4)) ^ (lane & 7)) * 8;  // swizzled read granule
      bf16x8 af[FM], bfr[FN];
#pragma unroll
      for (int m = 0; m < FM; ++m)
        af[m] = *reinterpret_cast<const bf16x8*>(
            &As[(wr * WM + m * 16 + (lane & 15)) * BK + g]);
#pragma unroll
      for (int n = 0; n < FN; ++n)
        bfr[n] = *reinterpret_cast<const bf16x8*>(
            &Bs[(wc * WN + n * 16 + (lane & 15)) * BK + g]);
#pragma unroll
      for (int m = 0; m < FM; ++m)
#pragma unroll
        for (int n = 0; n < FN; ++n)
          acc[m][n] = __builtin_amdgcn_mfma_f32_16x16x32_bf16(af[m], bfr[n], acc[m][n], 0, 0, 0);
    }
  }

  int lr4 = (lane >> 4) * 4, lc = lane & 15;
  if constexpr (EPI == 3) {
    float bb[FN];
#pragma unroll
    for (int n = 0; n < FN; ++n) bb[n] = bias[col0 + wc * WN + n * 16 + lc];
    int p = (col0 + wc * WN) >> 6;  // WN == 64
#pragma unroll
    for (int m = 0; m < FM; ++m) {
#pragma unroll
      for (int j = 0; j < 4; ++j) {
        int r = row0 + wr * WM + m * 16 + lr4 + j;
        float vs[FN], vmax = -1e30f;
#pragma unroll
        for (int n = 0; n < FN; ++n) {
          vs[n] = acc[m][n][j] + bb[n];
          vmax = fmaxf(vmax, vs[n]);
        }
#pragma unroll
        for (int off = 8; off >= 1; off >>= 1) vmax = fmaxf(vmax, __shfl_xor(vmax, off));
        float se = 0.f;
#pragma unroll
        for (int n = 0; n < FN; ++n) se += expf(vs[n] - vmax);
#pragma unroll
        for (int off = 8; off >= 1; off >>= 1) se += __shfl_xor(se, off);
        if (lc == 0) {
          pmax[(size_t)r * NP + p] = vmax;
          psum[(size_t)r * NP + p] = se;
        }
      }
    }
  } else {
#pragma unroll
    for (int m = 0; m < FM; ++m)
#pragma unroll
      for (int n = 0; n < FN; ++n) {
        int cg = col0 + wc * WN + n * 16 + lc;
        float bcol = bias[cg];
#pragma unroll
        for (int j = 0; j < 4; ++j) {
          int r = row0 + wr * WM + m * 16 + lr4 + j;
          float v = acc[m][n][j] + bcol;
          if constexpr (EPI == 0) ((float*)C)[(size_t)r * ldc + cg] = v;
          else ((unsigned short*)C)[(size_t)r * ldc + cg] = f2b(v);
        }
      }
  }
}

// ---------- persistent RNN: all 32 steps, one dispatch ----------
// 128 blocks = 4 n-groups(32 rows) x 32 h-groups(32 cols). Wh slice LDS-resident.
// Barrier v2: per-n-group (32 blocks), 1 poller/block, padded cells,
// release-add / relaxed-poll / single acquire (no standalone threadfence).
__global__ __launch_bounds__(256, 1) void k_rnn_persist(
    const unsigned short* __restrict__ h0B,
    const unsigned short* __restrict__ WhT,   // [outcol][k] bf16
    const float* __restrict__ xW,             // [R][H] f32
    unsigned short* __restrict__ HALLB,       // [R][H] bf16
    int* __restrict__ cells) {
  __shared__ __align__(16) unsigned short WhS[32 * 1024];
  __shared__ __align__(16) unsigned short AS[32 * 1024];
  const int tid = threadIdx.x, lane = tid & 63, wave = tid >> 6;
  const int bn = blockIdx.x >> 5, bh = blockIdx.x & 31;
  const int n0 = bn * 32, c0 = bh * 32;
  const int wr = wave >> 1, wc = wave & 1;
  const int hi = lane >> 4, lo = lane & 15;
  int* const cell = &cells[bn * 128];   // 512B-padded per-group barrier cell

  // stage Wh slice once, swizzled: LDS granule g of row r <- src granule g^(r&7)
  for (int c = wave; c < 64; c += 4) {
    int row = c >> 1, half = c & 1;
    int sg = (half * 64 + lane) ^ (row & 7);
    GLOAD_LDS16(WhT + (size_t)(c0 + row) * 1024 + sg * 8,
                WhS + row * 1024 + half * 512);
  }

  const int acol = c0 + wc * 16 + lo;
  const unsigned short* ar = AS + (size_t)(wr * 16 + lo) * 1024;
  const unsigned short* br = WhS + (size_t)(wc * 16 + lo) * 1024;

  for (int t = 0; t < T; ++t) {
    const unsigned short* Abase = (t == 0) ? h0B : (HALLB + (size_t)(t - 1) * H);
    size_t astr = (t == 0) ? (size_t)H : (size_t)T * H;
    for (int c = wave; c < 64; c += 4) {
      int row = c >> 1, half = c & 1;
      int sg = (half * 64 + lane) ^ (row & 7);
      GLOAD_LDS16(Abase + (size_t)(n0 + row) * astr + sg * 8,
                  AS + row * 1024 + half * 512);
    }
    float xw[4];
#pragma unroll
    for (int j = 0; j < 4; ++j)
      xw[j] = xW[(size_t)((n0 + wr * 16 + hi * 4 + j) * T + t) * H + acol];
    asm volatile("s_waitcnt vmcnt(0)" ::: "memory");
    __syncthreads();

    f32x4 acc = {0.f, 0.f, 0.f, 0.f};
#pragma unroll
    for (int kk = 0; kk < 32; ++kk) {
      int g = ((kk * 4 + hi) ^ (lane & 7)) * 8;
      bf16x8 af = *reinterpret_cast<const bf16x8*>(ar + g);
      bf16x8 bf_ = *reinterpret_cast<const bf16x8*>(br + g);
      acc = __builtin_amdgcn_mfma_f32_16x16x32_bf16(af, bf_, acc, 0, 0, 0);
    }
#pragma unroll
    for (int j = 0; j < 4; ++j) {
      float v = tanhf(acc[j] + xw[j]);
      HALLB[(size_t)((n0 + wr * 16 + hi * 4 + j) * T + t) * H + acol] = f2b(v);
    }
    if (t + 1 < T) {
      __syncthreads();   // all lanes' h stores drained (waitcnt before barrier)
      if (tid == 0) {
        // release: flush this XCD's dirty L2 (h_t) to the common point
        __hip_atomic_fetch_add(cell, 1, __ATOMIC_RELEASE, __HIP_MEMORY_SCOPE_AGENT);
        const int target = 32 * (t + 1);
        while (__hip_atomic_load(cell, __ATOMIC_RELAXED, __HIP_MEMORY_SCOPE_AGENT) < target)
          __builtin_amdgcn_s_sleep(4);
        // acquire: invalidate stale L1/L2 copies of h before re-reading
        (void)__hip_atomic_load(cell, __ATOMIC_ACQUIRE, __HIP_MEMORY_SCOPE_AGENT);
      }
      __syncthreads();
    }
  }
}

// ---------- combine partials + target dot -> per-block nll sums ----------
__global__ __launch_bounds__(256) void k_loss(const float* __restrict__ pmax,
                                              const float* __restrict__ psum,
                                              const unsigned short* __restrict__ HALLB,
                                              const unsigned short* __restrict__ WvT,
                                              const float* __restrict__ bv,
                                              const int* __restrict__ cap,
                                              float* __restrict__ blk) {
  int wave = threadIdx.x >> 6, lane = threadIdx.x & 63;
  int r = blockIdx.x * 4 + wave;
  float M = -1e30f;
  for (int i = lane; i < NP; i += 64) M = fmaxf(M, pmax[(size_t)r * NP + i]);
#pragma unroll
  for (int off = 32; off >= 1; off >>= 1) M = fmaxf(M, __shfl_xor(M, off));
  float S = 0.f;
  for (int i = lane; i < NP; i += 64) S += psum[(size_t)r * NP + i] * expf(pmax[(size_t)r * NP + i] - M);
#pragma unroll
  for (int off = 32; off >= 1; off >>= 1) S += __shfl_xor(S, off);
  float lse = M + logf(S);
  int n = r >> 5, t = r & 31;
  int tok = cap[n * 33 + t + 1];
  const unsigned short* hr = HALLB + (size_t)r * H + lane * 16;
  const unsigned short* wr_ = WvT + (size_t)tok * H + lane * 16;
  float d = 0.f;
#pragma unroll
  for (int i = 0; i < 16; ++i) d += b2f(hr[i]) * b2f(wr_[i]);
#pragma unroll
  for (int off = 32; off >= 1; off >>= 1) d += __shfl_xor(d, off);
  float nll = (tok != 0) ? (lse - (d + bv[tok])) : 0.f;
  __shared__ float red[4];
  if (lane == 0) red[wave] = nll;
  __syncthreads();
  if (threadIdx.x == 0) blk[blockIdx.x] = red[0] + red[1] + red[2] + red[3];
}

__global__ __launch_bounds__(256) void k_final(const float* __restrict__ blk,
                                               float* __restrict__ out) {
  __shared__ float red[256];
  float s = 0.f;
  for (int i = threadIdx.x; i < R / 4; i += 256) s += blk[i];
  red[threadIdx.x] = s;
  __syncthreads();
  for (int st = 128; st >= 1; st >>= 1) {
    if (threadIdx.x < st) red[threadIdx.x] += red[threadIdx.x + st];
    __syncthreads();
  }
  if (threadIdx.x == 0) out[0] = red[0] * (1.0f / 128.0f);
}

}  // namespace

extern "C" void kernel_launch(void* const* d_in, const int* in_sizes, int n_in,
                              void* d_out, int out_size, void* d_ws, size_t ws_size,
                              hipStream_t stream) {
  const float* feat = (const float*)d_in[0];
  const int*   cap  = (const int*)d_in[1];
  const float* Wp   = (const float*)d_in[2];
  const float* bp   = (const float*)d_in[3];
  const float* Wemb = (const float*)d_in[4];
  const float* Wx   = (const float*)d_in[5];
  const float* Wh   = (const float*)d_in[6];
  const float* b    = (const float*)d_in[7];
  const float* Wv   = (const float*)d_in[8];
  const float* bv   = (const float*)d_in[9];

  float* ws = (float*)d_ws;
  unsigned short* XB    = (unsigned short*)(ws + OFF_XB);
  unsigned short* featB = (unsigned short*)(ws + OFF_FEATB);
  unsigned short* h0B   = (unsigned short*)(ws + OFF_H0B);
  unsigned short* HALLB = (unsigned short*)(ws + OFF_HALLB);
  unsigned short* WpT   = (unsigned short*)(ws + OFF_WPT);
  unsigned short* WxT   = (unsigned short*)(ws + OFF_WXT);
  unsigned short* WhT   = (unsigned short*)(ws + OFF_WHT);
  unsigned short* WvT   = (unsigned short*)(ws + OFF_WVT);
  float* xW   = ws + OFF_XW;
  float* pmax = ws + OFF_PMAX;
  float* psum = ws + OFF_PSUM;
  float* blk  = ws + OFF_BLK;
  int*   bar  = (int*)(ws + OFF_BAR);

  hipMemsetAsync(bar, 0, 512 * sizeof(int), stream);

  // weight converts/transposes (bf16, B^T layout)
  hipLaunchKernelGGL(k_cvt_t, dim3(H / 32, D / 32), dim3(256), 0, stream, Wp, WpT, D, H);
  hipLaunchKernelGGL(k_cvt_t, dim3(H / 32, D / 32), dim3(256), 0, stream, Wx, WxT, D, H);
  hipLaunchKernelGGL(k_cvt_t, dim3(H / 32, H / 32), dim3(256), 0, stream, Wh, WhT, H, H);
  hipLaunchKernelGGL(k_cvt_t, dim3(V / 32, H / 32), dim3(256), 0, stream, Wv, WvT, H, V);
  hipLaunchKernelGGL(k_cvt, dim3(N * D / 512), dim3(256), 0, stream, feat, featB);
  hipLaunchKernelGGL(k_gather, dim3(R * D / 512), dim3(256), 0, stream, cap, Wemb, XB);

  // h0 = featB @ Wp^T + bp   (bf16 out)
  hipLaunchKernelGGL((gemm_bt<128, 128, 64, 64, 1>), dim3(H / 128, 1), dim3(256), 0, stream,
                     featB, D, WpT, D, (void*)h0B, H, bp, nullptr, nullptr);
  // xW = XB @ Wx^T + b   (f32 out)
  hipLaunchKernelGGL((gemm_bt<128, 128, 64, 64, 0>), dim3(H / 128, R / 128), dim3(256), 0, stream,
                     XB, D, WxT, D, (void*)xW, H, b, nullptr, nullptr);
  // full recurrence in one persistent dispatch
  hipLaunchKernelGGL(k_rnn_persist, dim3(128), dim3(256), 0, stream,
                     h0B, WhT, xW, HALLB, bar);
  // scores partials
  hipLaunchKernelGGL((gemm_bt<128, 128, 64, 64, 3>), dim3(V / 128, R / 128), dim3(256), 0, stream,
                     HALLB, H, WvT, H, nullptr, 0, bv, pmax, psum);
  hipLaunchKernelGGL(k_loss, dim3(R / 4), dim3(256), 0, stream,
                     pmax, psum, HALLB, WvT, bv, cap, blk);
  hipLaunchKernelGGL(k_final, dim3(1), dim3(256), 0, stream, blk, (float*)d_out);
}